// Round 2
// baseline (414.414 us; speedup 1.0000x reference)
//
#include <hip/hip_runtime.h>
#include <hip/hip_bf16.h>

// B=16, N=256, A=64, D=256.  I = B*N = 4096 rows.
// Algebra:
//   M = Wq^T@Wk, r = bq@Wk, u = Wq^T@bk, s0 = bq.bk
//   t[i] = cc[i]@M + r,  c[i] = cc[i].u + s0
//   adj[i][a] = (anchor[i][a].t[i] + c[i])/16 + sims[i][a]
//   probs = conditional softmax; w[i] = sum_a p[a]*anchor[i][a]; psum = sum p
//   out[i][d] = sum_e w[i][e]*WvT[e][d] + bv[d]*psum[i]
//
// Fused version: former K2 (t-projection), K3 (attention) and K4 (output GEMV)
// are one kernel; t8/c8/w8/psum live in LDS only, removing the tmat/wmat HBM
// round-trips and two kernel-boundary serializations. The L2-resident M/WvT
// GEMVs overlap with the 256 MB anchor stream (~42 us irreducible floor).

typedef float f4 __attribute__((ext_vector_type(4)));

__device__ __forceinline__ float bcast_lane(float x, int lane) {
  return __int_as_float(__builtin_amdgcn_readlane(__float_as_int(x), lane));
}

// ---------------- K1: weight prep (unchanged) ----------------
__global__ __launch_bounds__(256) void k1_prep(
    const float* __restrict__ Wq, const float* __restrict__ bq,
    const float* __restrict__ Wk, const float* __restrict__ bk,
    const float* __restrict__ Wv,
    float* __restrict__ M, float* __restrict__ rvec, float* __restrict__ uvec,
    float* __restrict__ s0, float* __restrict__ WvT) {
  __shared__ float colL[256];
  __shared__ float pr[256];
  __shared__ float tile[64][65];
  const int tid = threadIdx.x;
  const int bid = blockIdx.x;
  if (bid < 256) {
    colL[tid] = Wq[tid * 256 + bid];
    __syncthreads();
    float acc = 0.f;
#pragma unroll 4
    for (int d = 0; d < 256; ++d) acc += colL[d] * Wk[d * 256 + tid];
    M[bid * 256 + tid] = acc;
  } else if (bid == 256) {
    colL[tid] = bq[tid];
    __syncthreads();
    float acc = 0.f;
#pragma unroll 4
    for (int d = 0; d < 256; ++d) acc += colL[d] * Wk[d * 256 + tid];
    rvec[tid] = acc;
  } else if (bid == 257) {
    colL[tid] = bk[tid];
    pr[tid] = bq[tid] * bk[tid];
    __syncthreads();
    float acc = 0.f;
#pragma unroll 4
    for (int d = 0; d < 256; ++d) acc += Wq[d * 256 + tid] * colL[d];
    uvec[tid] = acc;
    if (tid == 0) {
      float s = 0.f;
      for (int d = 0; d < 256; ++d) s += pr[d];
      s0[0] = s;
    }
  } else {
    const int tb = bid - 258, bi = tb >> 2, bj = tb & 3;
#pragma unroll
    for (int k = 0; k < 16; ++k) {
      int idx = k * 256 + tid;
      int r = idx >> 6, cL = idx & 63;
      tile[r][cL] = Wv[(bi * 64 + r) * 256 + bj * 64 + cL];
    }
    __syncthreads();
#pragma unroll
    for (int k = 0; k < 16; ++k) {
      int idx = k * 256 + tid;
      int r = idx >> 6, cL = idx & 63;
      WvT[(bj * 64 + r) * 256 + bi * 64 + cL] = tile[cL][r];
    }
  }
}

// ---------------- K_main: fused projection + attention + output -------------
// 512 blocks x 256 threads, 8 rows per block (exactly 2 blocks/CU, all
// co-resident). Phase 1: t8 = cc8@M + r, c8 = cc8.u + s0 (M from L2).
// Phase 2: per row, stream anchor (64 KB) into registers (nontemporal),
// scores -> conditional softmax -> weighted sum, with next-row prefetch.
// Phase 3: out8 = w8@WvT + bv*psum8 (WvT from L2).
__global__ __launch_bounds__(256) void k_main(
    const float* __restrict__ cc, const float* __restrict__ anchor,
    const float* __restrict__ sims,
    const float* __restrict__ M, const float* __restrict__ rvec,
    const float* __restrict__ uvec, const float* __restrict__ s0p,
    const float* __restrict__ WvT, const float* __restrict__ bv,
    float* __restrict__ out) {
  __shared__ __align__(16) float pOut[4][8][256];  // 32 KB partials (ph1/ph3), pW alias (ph2)
  __shared__ __align__(16) float t8[8][256];       // 8 KB t-vectors
  __shared__ __align__(16) float w8[8][256];       // 8 KB weighted anchor sums
  __shared__ float cpart[4][8];
  __shared__ float c8[8];
  __shared__ float ps8[8];
  __shared__ float sL[64];
  __shared__ float pL[64];
  const int tid = threadIdx.x;
  const int w = tid >> 6, L = tid & 63;
  const int i0 = blockIdx.x * 8;
  const int e0 = w * 64;

  // ---- Phase 1: t8 = cc8 @ M + r ; c8 = cc8 . u + s0 (K2 pattern)
  float ccreg[8];
#pragma unroll
  for (int r = 0; r < 8; ++r) ccreg[r] = cc[(size_t)(i0 + r) * 256 + e0 + L];
  float uvl = uvec[e0 + L];
  {
    f4 acc[8] = {};
#pragma unroll 8
    for (int ee = 0; ee < 64; ++ee) {
      f4 m = *(const f4*)(M + (size_t)(e0 + ee) * 256 + 4 * L);
#pragma unroll
      for (int r = 0; r < 8; ++r) {
        float cv = bcast_lane(ccreg[r], ee);
        acc[r].x += cv * m.x; acc[r].y += cv * m.y;
        acc[r].z += cv * m.z; acc[r].w += cv * m.w;
      }
    }
#pragma unroll
    for (int r = 0; r < 8; ++r) *(f4*)&pOut[w][r][4 * L] = acc[r];
#pragma unroll
    for (int r = 0; r < 8; ++r) {
      float pc = ccreg[r] * uvl;
#pragma unroll
      for (int off = 32; off >= 1; off >>= 1) pc += __shfl_xor(pc, off, 64);
      if (L == 0) cpart[w][r] = pc;
    }
  }

  // Issue row-0 anchor loads early: overlap t8 reduce + sync + score wait.
  // Nontemporal: zero-reuse 256 MB stream — don't thrash L2.
  const f4* g4 = (const f4*)(anchor + (size_t)i0 * 16384);
  f4 v[16];
#pragma unroll
  for (int k = 0; k < 16; ++k) v[k] = __builtin_nontemporal_load(g4 + k * 256 + tid);

  __syncthreads();
  {
    float rv = rvec[tid];
#pragma unroll
    for (int r = 0; r < 8; ++r)
      t8[r][tid] = pOut[0][r][tid] + pOut[1][r][tid] + pOut[2][r][tid] +
                   pOut[3][r][tid] + rv;
    if (tid < 8)
      c8[tid] = cpart[0][tid] + cpart[1][tid] + cpart[2][tid] + cpart[3][tid] + s0p[0];
  }
  __syncthreads();

  // ---- Phase 2: per-row attention (K3 pattern), rows sequential with prefetch
  float* pW = &pOut[0][0][0];  // [4][256] alias, free between phase-1 and phase-3
  for (int r = 0; r < 8; ++r) {
    const f4 t4 = *(const f4*)&t8[r][4 * L];
    // scores: per-k 4 FMA then 64-lane butterfly reduce
#pragma unroll
    for (int k = 0; k < 16; ++k) {
      float s = v[k].x * t4.x + v[k].y * t4.y + v[k].z * t4.z + v[k].w * t4.w;
#pragma unroll
      for (int off = 32; off >= 1; off >>= 1) s += __shfl_xor(s, off, 64);
      if (L == 0) sL[k * 4 + w] = s;
    }
    __syncthreads();
    if (tid < 64) {
      float adj = (sL[tid] + c8[r]) * 0.0625f + sims[(size_t)(i0 + r) * 64 + tid];
      float ssum = adj, smax = adj;
#pragma unroll
      for (int off = 32; off >= 1; off >>= 1) {
        ssum += __shfl_xor(ssum, off, 64);
        smax = fmaxf(smax, __shfl_xor(smax, off, 64));
      }
      float p;
      if (ssum != 0.f) {
        p = expf(adj - smax);
        float z = p;
#pragma unroll
        for (int off = 32; off >= 1; off >>= 1) z += __shfl_xor(z, off, 64);
        p = p / z;
      } else {
        p = adj;  // pass-through row
      }
      float ps = p;
#pragma unroll
      for (int off = 32; off >= 1; off >>= 1) ps += __shfl_xor(ps, off, 64);
      pL[tid] = p;
      if (tid == 0) ps8[r] = ps;
    }
    __syncthreads();
    // weighted anchor sum from registers; prob via LDS broadcast
    f4 acc = {0.f, 0.f, 0.f, 0.f};
#pragma unroll
    for (int k = 0; k < 16; ++k) {
      float p = pL[k * 4 + w];
      acc.x += p * v[k].x; acc.y += p * v[k].y;
      acc.z += p * v[k].z; acc.w += p * v[k].w;
    }
    // prefetch next row's anchor tile (v regs now dead)
    if (r < 7) {
      const f4* g4n = (const f4*)(anchor + (size_t)(i0 + r + 1) * 16384);
#pragma unroll
      for (int k = 0; k < 16; ++k)
        v[k] = __builtin_nontemporal_load(g4n + k * 256 + tid);
    }
    *(f4*)&pW[w * 256 + 4 * L] = acc;
    __syncthreads();
    w8[r][tid] = pW[tid] + pW[256 + tid] + pW[512 + tid] + pW[768 + tid];
    // no barrier needed here: next row's first pW write is fenced by two
    // syncthreads (score->softmax->wsum), and sL readers finished pre-sync.
  }
  __syncthreads();

  // ---- Phase 3: out8 = w8 @ WvT + bv*psum8 (K4 pattern)
  {
    float wreg[8];
#pragma unroll
    for (int r = 0; r < 8; ++r) wreg[r] = w8[r][e0 + L];
    f4 acc[8] = {};
#pragma unroll 8
    for (int ee = 0; ee < 64; ++ee) {
      f4 m = *(const f4*)(WvT + (size_t)(e0 + ee) * 256 + 4 * L);
#pragma unroll
      for (int r = 0; r < 8; ++r) {
        float cv = bcast_lane(wreg[r], ee);
        acc[r].x += cv * m.x; acc[r].y += cv * m.y;
        acc[r].z += cv * m.z; acc[r].w += cv * m.w;
      }
    }
#pragma unroll
    for (int r = 0; r < 8; ++r) *(f4*)&pOut[w][r][4 * L] = acc[r];
  }
  __syncthreads();
  {
    float b = bv[tid];
#pragma unroll
    for (int r = 0; r < 8; ++r) {
      float s = pOut[0][r][tid] + pOut[1][r][tid] + pOut[2][r][tid] + pOut[3][r][tid];
      out[(size_t)(i0 + r) * 256 + tid] = s + b * ps8[r];
    }
  }
}

extern "C" void kernel_launch(void* const* d_in, const int* in_sizes, int n_in,
                              void* d_out, int out_size, void* d_ws, size_t ws_size,
                              hipStream_t stream) {
  const float* cc     = (const float*)d_in[0];  // [16,256,256]
  const float* anchor = (const float*)d_in[1];  // [16,256,64,256]
  const float* sims   = (const float*)d_in[2];  // [16,256,64]
  const float* Wq     = (const float*)d_in[3];
  const float* bq     = (const float*)d_in[4];
  const float* Wk     = (const float*)d_in[5];
  const float* bk     = (const float*)d_in[6];
  const float* Wv     = (const float*)d_in[7];
  const float* bv     = (const float*)d_in[8];
  float* out = (float*)d_out;
  float* ws  = (float*)d_ws;

  float* M    = ws;                 // 65536
  float* WvT  = ws + 65536;         // 65536
  float* rvec = ws + 131072;        // 256
  float* uvec = ws + 131328;        // 256
  float* s0   = ws + 131584;        // 256 (pad)

  k1_prep<<<274, 256, 0, stream>>>(Wq, bq, Wk, bk, Wv, M, rvec, uvec, s0, WvT);
  k_main<<<512, 256, 0, stream>>>(cc, anchor, sims, M, rvec, uvec, s0, WvT, bv, out);
}

// Round 3
// 412.378 us; speedup vs baseline: 1.0049x; 1.0049x over previous
//
#include <hip/hip_runtime.h>

// B=16, N=256, A=64, D=256.  I = B*N = 4096 rows.
// Algebra:
//   M = Wq^T@Wk, r = bq@Wk, u = Wq^T@bk, s0 = bq.bk
//   t[i] = cc[i]@M + r,  c[i] = cc[i].u + s0
//   adj[i][a] = (anchor[i][a].t[i] + c[i])/16 + sims[i][a]
//   probs = conditional softmax; w[i] = sum_a p[a]*anchor[i][a]; psum = sum p
//   out[i][d] = sum_e w[i][e]*WvT[e][d] + bv[d]*psum[i]
//
// R2: k_main keeps anchor loads in flight across barriers.
//   - raw s_barrier + lgkmcnt(0) only (no vmcnt(0) drain: cross-wave traffic
//     is LDS-only; anchor loads land in private VGPRs)
//   - 1 barrier/row in phase 2 (redundant per-wave softmax + readlane p
//     broadcast + deferred pOut reduce)
//   - vA/vB double-buffered anchor rows; row r+2 issued after row r's wsum
//     (issue-to-use distance ~1 row body ~ HBM latency)

typedef float f4 __attribute__((ext_vector_type(4)));

__device__ __forceinline__ float bcast_lane(float x, int lane) {
  return __int_as_float(__builtin_amdgcn_readlane(__float_as_int(x), lane));
}

// LDS-only block barrier: drains ds ops, NOT vmcnt (prefetch stays in flight).
__device__ __forceinline__ void sync_lds() {
  asm volatile("s_waitcnt lgkmcnt(0)" ::: "memory");
  __builtin_amdgcn_s_barrier();
  __builtin_amdgcn_sched_barrier(0);
}

// ---------------- K1: weight prep (unchanged) ----------------
__global__ __launch_bounds__(256) void k1_prep(
    const float* __restrict__ Wq, const float* __restrict__ bq,
    const float* __restrict__ Wk, const float* __restrict__ bk,
    const float* __restrict__ Wv,
    float* __restrict__ M, float* __restrict__ rvec, float* __restrict__ uvec,
    float* __restrict__ s0, float* __restrict__ WvT) {
  __shared__ float colL[256];
  __shared__ float pr[256];
  __shared__ float tile[64][65];
  const int tid = threadIdx.x;
  const int bid = blockIdx.x;
  if (bid < 256) {
    colL[tid] = Wq[tid * 256 + bid];
    __syncthreads();
    float acc = 0.f;
#pragma unroll 4
    for (int d = 0; d < 256; ++d) acc += colL[d] * Wk[d * 256 + tid];
    M[bid * 256 + tid] = acc;
  } else if (bid == 256) {
    colL[tid] = bq[tid];
    __syncthreads();
    float acc = 0.f;
#pragma unroll 4
    for (int d = 0; d < 256; ++d) acc += colL[d] * Wk[d * 256 + tid];
    rvec[tid] = acc;
  } else if (bid == 257) {
    colL[tid] = bk[tid];
    pr[tid] = bq[tid] * bk[tid];
    __syncthreads();
    float acc = 0.f;
#pragma unroll 4
    for (int d = 0; d < 256; ++d) acc += Wq[d * 256 + tid] * colL[d];
    uvec[tid] = acc;
    if (tid == 0) {
      float s = 0.f;
      for (int d = 0; d < 256; ++d) s += pr[d];
      s0[0] = s;
    }
  } else {
    const int tb = bid - 258, bi = tb >> 2, bj = tb & 3;
#pragma unroll
    for (int k = 0; k < 16; ++k) {
      int idx = k * 256 + tid;
      int r = idx >> 6, cL = idx & 63;
      tile[r][cL] = Wv[(bi * 64 + r) * 256 + bj * 64 + cL];
    }
    __syncthreads();
#pragma unroll
    for (int k = 0; k < 16; ++k) {
      int idx = k * 256 + tid;
      int r = idx >> 6, cL = idx & 63;
      WvT[(bj * 64 + r) * 256 + bi * 64 + cL] = tile[cL][r];
    }
  }
}

// Row body: scores -> (1 barrier) -> redundant softmax in all waves ->
// wsum partial into pOut[w][R] (no barrier) -> prefetch next+1 row into CUR.
#define ROW_BODY(R, CUR, PREFETCH_STMT)                                       \
  {                                                                           \
    const f4 t4 = *(const f4*)&t8[R][4 * L];                                  \
    _Pragma("unroll")                                                         \
    for (int k = 0; k < 16; ++k) {                                            \
      float s = CUR[k].x * t4.x + CUR[k].y * t4.y + CUR[k].z * t4.z +         \
                CUR[k].w * t4.w;                                              \
      _Pragma("unroll")                                                       \
      for (int off = 32; off >= 1; off >>= 1) s += __shfl_xor(s, off, 64);    \
      if (L == 0) sL8[R][k * 4 + w] = s;                                      \
    }                                                                         \
    sync_lds();                                                               \
    float adj = (sL8[R][L] + c8[R]) * 0.0625f + simsL[R * 64 + L];            \
    float ssum = adj, smax = adj;                                             \
    _Pragma("unroll")                                                         \
    for (int off = 32; off >= 1; off >>= 1) {                                 \
      ssum += __shfl_xor(ssum, off, 64);                                      \
      smax = fmaxf(smax, __shfl_xor(smax, off, 64));                          \
    }                                                                         \
    float p;                                                                  \
    if (ssum != 0.f) {                                                        \
      p = expf(adj - smax);                                                   \
      float z = p;                                                            \
      _Pragma("unroll")                                                       \
      for (int off = 32; off >= 1; off >>= 1) z += __shfl_xor(z, off, 64);    \
      p = p / z;                                                              \
    } else {                                                                  \
      p = adj; /* pass-through row */                                         \
    }                                                                         \
    float ps = p;                                                             \
    _Pragma("unroll")                                                         \
    for (int off = 32; off >= 1; off >>= 1) ps += __shfl_xor(ps, off, 64);    \
    psr[R] = ps;                                                              \
    f4 acc = {0.f, 0.f, 0.f, 0.f};                                            \
    _Pragma("unroll")                                                         \
    for (int k = 0; k < 16; ++k) {                                            \
      float pk = bcast_lane(p, k * 4 + w);                                    \
      acc.x += pk * CUR[k].x; acc.y += pk * CUR[k].y;                         \
      acc.z += pk * CUR[k].z; acc.w += pk * CUR[k].w;                         \
    }                                                                         \
    PREFETCH_STMT;                                                            \
    *(f4*)&pOut[w][R][4 * L] = acc;                                           \
  }

#define PF(RN, CUR)                                                           \
  {                                                                           \
    const f4* gn = g4 + (size_t)(RN)*4096;                                    \
    _Pragma("unroll")                                                         \
    for (int k = 0; k < 16; ++k)                                              \
      CUR[k] = __builtin_nontemporal_load(gn + k * 256 + tid);                \
  }

// ---------------- K_main: fused projection + attention + output -------------
// 512 blocks x 256 threads (2 blocks/CU), 8 rows/block.
__global__ __launch_bounds__(256, 2) void k_main(
    const float* __restrict__ cc, const float* __restrict__ anchor,
    const float* __restrict__ sims,
    const float* __restrict__ M, const float* __restrict__ rvec,
    const float* __restrict__ uvec, const float* __restrict__ s0p,
    const float* __restrict__ WvT, const float* __restrict__ bv,
    float* __restrict__ out) {
  __shared__ __align__(16) float pOut[4][8][256];  // 32 KB: ph1 GEMV partials, ph2 wsum partials, ph3 GEMV partials
  __shared__ __align__(16) float t8[8][256];       // 8 KB t-vectors
  __shared__ float sL8[8][64];                     // per-row raw scores
  __shared__ float simsL[512];                     // sims staging
  __shared__ float cpart[4][8];
  __shared__ float c8[8];
  const int tid = threadIdx.x;
  const int w = tid >> 6, L = tid & 63;
  const int i0 = blockIdx.x * 8;
  const int e0 = w * 64;

  // ---- Phase 0: issue all phase-1-consumed loads BEFORE anchor prefetch
  // (vmcnt is FIFO: anchor loads issued first would head-of-line-block the
  // GEMV's M-load waits).
  float ccreg[8];
#pragma unroll
  for (int r = 0; r < 8; ++r) ccreg[r] = cc[(size_t)(i0 + r) * 256 + e0 + L];
  float uvl = uvec[e0 + L];
  float rv_ = rvec[tid];
  float s0v = s0p[0];
  simsL[tid] = sims[(size_t)i0 * 64 + tid];
  simsL[256 + tid] = sims[(size_t)i0 * 64 + 256 + tid];

  // ---- Phase 1: t8 = cc8 @ M + r ; c8 = cc8 . u + s0
  {
    f4 acc[8] = {};
#pragma unroll 8
    for (int ee = 0; ee < 64; ++ee) {
      f4 m = *(const f4*)(M + (size_t)(e0 + ee) * 256 + 4 * L);
#pragma unroll
      for (int r = 0; r < 8; ++r) {
        float cv = bcast_lane(ccreg[r], ee);
        acc[r].x += cv * m.x; acc[r].y += cv * m.y;
        acc[r].z += cv * m.z; acc[r].w += cv * m.w;
      }
    }
#pragma unroll
    for (int r = 0; r < 8; ++r) *(f4*)&pOut[w][r][4 * L] = acc[r];
#pragma unroll
    for (int r = 0; r < 8; ++r) {
      float pc = ccreg[r] * uvl;
#pragma unroll
      for (int off = 32; off >= 1; off >>= 1) pc += __shfl_xor(pc, off, 64);
      if (L == 0) cpart[w][r] = pc;
    }
  }

  // Issue anchor rows 0,1 (stay in flight across the lgkm-only barriers;
  // nontemporal: zero-reuse 256 MB stream, don't thrash L2).
  const f4* g4 = (const f4*)(anchor + (size_t)i0 * 16384);
  f4 vA[16], vB[16];
  PF(0, vA);
  PF(1, vB);

  sync_lds();
#pragma unroll
  for (int r = 0; r < 8; ++r)
    t8[r][tid] = pOut[0][r][tid] + pOut[1][r][tid] + pOut[2][r][tid] +
                 pOut[3][r][tid] + rv_;
  if (tid < 8)
    c8[tid] = cpart[0][tid] + cpart[1][tid] + cpart[2][tid] + cpart[3][tid] + s0v;
  sync_lds();

  // ---- Phase 2: 8 rows, 1 lgkm-only barrier each, double-buffered loads
  float psr[8];
  ROW_BODY(0, vA, PF(2, vA));
  ROW_BODY(1, vB, PF(3, vB));
  ROW_BODY(2, vA, PF(4, vA));
  ROW_BODY(3, vB, PF(5, vB));
  ROW_BODY(4, vA, PF(6, vA));
  ROW_BODY(5, vB, PF(7, vB));
  ROW_BODY(6, vA, );
  ROW_BODY(7, vB, );

  sync_lds();  // all pOut[w][r] wsum partials visible

  // ---- Phase 3: out8 = w8 @ WvT + bv*psum8
  float wreg[8];
#pragma unroll
  for (int r = 0; r < 8; ++r)
    wreg[r] = pOut[0][r][e0 + L] + pOut[1][r][e0 + L] + pOut[2][r][e0 + L] +
              pOut[3][r][e0 + L];
  float bvv = bv[tid];
  sync_lds();  // wreg reads done before pOut overwrite
  {
    f4 acc[8] = {};
#pragma unroll 8
    for (int ee = 0; ee < 64; ++ee) {
      f4 m = *(const f4*)(WvT + (size_t)(e0 + ee) * 256 + 4 * L);
#pragma unroll
      for (int r = 0; r < 8; ++r) {
        float cv = bcast_lane(wreg[r], ee);
        acc[r].x += cv * m.x; acc[r].y += cv * m.y;
        acc[r].z += cv * m.z; acc[r].w += cv * m.w;
      }
    }
#pragma unroll
    for (int r = 0; r < 8; ++r) *(f4*)&pOut[w][r][4 * L] = acc[r];
  }
  sync_lds();
#pragma unroll
  for (int r = 0; r < 8; ++r) {
    float s = pOut[0][r][tid] + pOut[1][r][tid] + pOut[2][r][tid] + pOut[3][r][tid];
    out[(size_t)(i0 + r) * 256 + tid] = s + bvv * psr[r];
  }
}

extern "C" void kernel_launch(void* const* d_in, const int* in_sizes, int n_in,
                              void* d_out, int out_size, void* d_ws, size_t ws_size,
                              hipStream_t stream) {
  const float* cc     = (const float*)d_in[0];  // [16,256,256]
  const float* anchor = (const float*)d_in[1];  // [16,256,64,256]
  const float* sims   = (const float*)d_in[2];  // [16,256,64]
  const float* Wq     = (const float*)d_in[3];
  const float* bq     = (const float*)d_in[4];
  const float* Wk     = (const float*)d_in[5];
  const float* bk     = (const float*)d_in[6];
  const float* Wv     = (const float*)d_in[7];
  const float* bv     = (const float*)d_in[8];
  float* out = (float*)d_out;
  float* ws  = (float*)d_ws;

  float* M    = ws;                 // 65536
  float* WvT  = ws + 65536;         // 65536
  float* rvec = ws + 131072;        // 256
  float* uvec = ws + 131328;        // 256
  float* s0   = ws + 131584;        // 256 (pad)

  k1_prep<<<274, 256, 0, stream>>>(Wq, bq, Wk, bk, Wv, M, rvec, uvec, s0, WvT);
  k_main<<<512, 256, 0, stream>>>(cc, anchor, sims, M, rvec, uvec, s0, WvT, bv, out);
}